// Round 2
// baseline (250.260 us; speedup 1.0000x reference)
//
#include <hip/hip_runtime.h>

#define Bb 8
#define Cc 64
#define Hh 200
#define Ww 320
#define Nn 48
#define WDd 80
#define HW (Hh*Ww)

// ---------------------------------------------------------------------------
// Kernel 1: per (b,n) block of 256 threads.
//   phase A: mean over WD of kernel_feats[b,:,idx,:]  (float4, 4-way split)
//   phase B: vk = Wk·kfm + bk            (65 outputs, float4 weight loads)
//   phase C: WeffT[b][c'][n] = vk·Wf[:,c'] ; beff = vk·bf + vk[64]; centers
// ---------------------------------------------------------------------------
__global__ __launch_bounds__(256) void prep_kernel(
    const float* __restrict__ kf, const float* __restrict__ Wk,
    const float* __restrict__ bk, const float* __restrict__ Wf,
    const float* __restrict__ bf, const float* __restrict__ db,
    const int* __restrict__ pad_w,
    float* __restrict__ weffT, float* __restrict__ beff,
    float* __restrict__ centers)
{
    const int n = blockIdx.x, b = blockIdx.y, tid = threadIdx.x;
    const int c = tid & 63, q = tid >> 6;
    const float stride = (float)pad_w[0] / (float)Ww;   // 4.0
    const float yc = (db[(b*Nn + n)*4 + 1] + db[(b*Nn + n)*4 + 3]) / (2.0f * stride);
    const int idx = (int)yc;

    __shared__ float part[Cc][5];   // padded: bank = (5c+q)%32, 2-way max (free)
    __shared__ float kfm[Cc];
    __shared__ float vk[Cc + 1];

    // phase A: each (c,q) sums 20 floats = 5 float4 (row is 16B-aligned)
    {
        const float4* row = (const float4*)(kf + ((size_t)(b*Cc + c)*Hh + idx)*WDd) + q*5;
        float4 v0 = row[0], v1 = row[1], v2 = row[2], v3 = row[3], v4 = row[4];
        float s = (v0.x+v0.y+v0.z+v0.w) + (v1.x+v1.y+v1.z+v1.w)
                + (v2.x+v2.y+v2.z+v2.w) + (v3.x+v3.y+v3.z+v3.w)
                + (v4.x+v4.y+v4.z+v4.w);
        part[c][q] = s;
    }
    __syncthreads();
    if (tid < Cc)
        kfm[tid] = (part[tid][0]+part[tid][1]+part[tid][2]+part[tid][3]) * (1.0f/(float)WDd);
    __syncthreads();

    // phase B: vk[o] = bk[o] + Wk[o,:]·kfm   (o = tid for tid < 65)
    if (tid < Cc + 1) {
        float a = bk[tid];
        const float4* wr = (const float4*)(Wk + tid*Cc);   // 256B-aligned rows
        #pragma unroll
        for (int i = 0; i < 16; ++i) {
            float4 wv = wr[i];
            a = fmaf(wv.x, kfm[4*i+0], a);
            a = fmaf(wv.y, kfm[4*i+1], a);
            a = fmaf(wv.z, kfm[4*i+2], a);
            a = fmaf(wv.w, kfm[4*i+3], a);
        }
        vk[tid] = a;
    }
    __syncthreads();

    // phase C
    if (tid < Cc) {
        float wsum = 0.f;
        #pragma unroll 8
        for (int c2 = 0; c2 < Cc; ++c2) wsum = fmaf(vk[c2], Wf[c2*Cc + tid], wsum);
        weffT[((size_t)b*Cc + tid)*Nn + n] = wsum;
    } else if (tid == Cc) {
        float bb2 = vk[Cc];
        #pragma unroll 8
        for (int c2 = 0; c2 < Cc; ++c2) bb2 = fmaf(vk[c2], bf[c2], bb2);
        beff[b*Nn + n] = bb2;
        centers[b*Nn + n] = yc * stride;
    }
}

// ---------------------------------------------------------------------------
// Kernel 2: logits[b,n,h,w] = sum_c WeffT[b][c][n]*feats[b,c,h,w] + beff[b,n]
// 2 pixels per lane (float2) -> v_pk_fma_f32, halved load/store inst count.
// One wave per 128 consecutive w; ballot makes the skip branch wave-uniform.
// ---------------------------------------------------------------------------
__global__ __launch_bounds__(64) void logits_kernel(
    const float* __restrict__ feats, const int* __restrict__ ishape,
    const int* __restrict__ pad_w, const float* __restrict__ weffT,
    const float* __restrict__ beff, float* __restrict__ out)
{
    const int b = blockIdx.z;
    const int h = blockIdx.y;
    const int w0 = blockIdx.x * 128 + threadIdx.x * 2;   // even

    const float stride = (float)pad_w[0] / (float)Ww;
    const int hlim = (int)((float)ishape[b*2 + 1] / stride);
    const int wlim = (int)((float)ishape[b*2 + 0] / stride);
    const bool inb  = (w0 < Ww);                          // w0 even -> w0+1 < Ww too
    const bool act0 = inb && (h < hlim) && (w0     < wlim);
    const bool act1 = inb && (h < hlim) && (w0 + 1 < wlim);

    float2 acc[Nn];
    if (__ballot(act0 || act1) != 0ULL) {                 // wave-uniform branch
        const float* __restrict__ bv = beff + b*Nn;
        #pragma unroll
        for (int n = 0; n < Nn; ++n) { acc[n].x = bv[n]; acc[n].y = bv[n]; }

        const float* __restrict__ fp = feats + ((size_t)(b*Cc)*Hh + h)*Ww + (inb ? w0 : 0);
        const float* __restrict__ wT = weffT + (size_t)b*Cc*Nn;
        #pragma unroll 4
        for (int c = 0; c < Cc; ++c) {
            const float2 fv = *(const float2*)(fp + (size_t)c * HW);
            const float* __restrict__ wrow = wT + c*Nn;
            #pragma unroll
            for (int n = 0; n < Nn; ++n) {
                acc[n].x = fmaf(wrow[n], fv.x, acc[n].x);
                acc[n].y = fmaf(wrow[n], fv.y, acc[n].y);
            }
        }
    } else {
        #pragma unroll
        for (int n = 0; n < Nn; ++n) { acc[n].x = -1e8f; acc[n].y = -1e8f; }
    }

    if (inb) {
        float* op = out + ((size_t)(b*Nn)*Hh + h)*Ww + w0;
        #pragma unroll
        for (int n = 0; n < Nn; ++n) {
            float2 v;
            v.x = act0 ? acc[n].x : -1e8f;
            v.y = act1 ? acc[n].y : -1e8f;
            *(float2*)(op + (size_t)n * HW) = v;
        }
    }
}

extern "C" void kernel_launch(void* const* d_in, const int* in_sizes, int n_in,
                              void* d_out, int out_size, void* d_ws, size_t ws_size,
                              hipStream_t stream) {
    const float* feats  = (const float*)d_in[0];
    const float* kf     = (const float*)d_in[1];
    const float* Wk     = (const float*)d_in[2];
    const float* bk     = (const float*)d_in[3];
    const float* Wf     = (const float*)d_in[4];
    const float* bf     = (const float*)d_in[5];
    const float* db     = (const float*)d_in[6];
    const int*   ishape = (const int*)d_in[7];
    const int*   pad_w  = (const int*)d_in[8];

    float* out    = (float*)d_out;
    float* weffT  = (float*)d_ws;                      // B*64*48 floats
    float* beff   = weffT + (size_t)Bb*Cc*Nn;          // B*48 floats
    float* centers = out + (size_t)Bb*Nn*Hh*Ww;        // second output

    prep_kernel<<<dim3(Nn, Bb), 256, 0, stream>>>(
        kf, Wk, bk, Wf, bf, db, pad_w, weffT, beff, centers);

    logits_kernel<<<dim3((Ww + 127)/128, Hh, Bb), 64, 0, stream>>>(
        feats, ishape, pad_w, weffT, beff, out);
}